// Round 11
// baseline (253.013 us; speedup 1.0000x reference)
//
#include <hip/hip_runtime.h>
#include <cstdint>
#include <cstddef>

#define IN_CH 128
#define HID_CH 128
#define OUT_CH 64
#define BSH 8        // nodes per bucket = 256
#define PB 4096      // edges per histogram/partition block

typedef unsigned int uint32;
typedef unsigned char uchar;
typedef short bf16x8 __attribute__((ext_vector_type(8)));
typedef float f32x4 __attribute__((ext_vector_type(4)));
typedef float f32x2 __attribute__((ext_vector_type(2)));

// float -> bf16 round-to-nearest-even
static __device__ __forceinline__ unsigned short f2bf(float f) {
    uint32 u = __float_as_uint(f);
    u += 0x7fffu + ((u >> 16) & 1u);
    return (unsigned short)(u >> 16);
}
// float -> fp8 e4m3 (OCP) single byte via HW cvt
static __device__ __forceinline__ uchar f2fp8(float f) {
    int p = __builtin_amdgcn_cvt_pk_fp8_f32(f, f, 0, false);
    return (uchar)(p & 0xff);
}

// ---------------- CSR build (bucketed, LDS-atomic only) ----------------

// bhist over buckets; wtrans fused into trailing blocks (independent work).
__global__ __launch_bounds__(256) void bhist_wtrans(
    const int* __restrict__ dst, int* __restrict__ bcnt, int E, int NB, int gP,
    const float* __restrict__ W1, const float* __restrict__ W2,
    unsigned short* __restrict__ W1t, unsigned short* __restrict__ W2t) {
    if (blockIdx.x >= (uint32)gP) {
        int t = (blockIdx.x - gP) * 256 + threadIdx.x;
        if (t < 128 * 128) {
            int nc = t >> 7, k = t & 127;
            W1t[t] = f2bf(W1[k * 128 + nc]);
        }
        int u = t - 128 * 128;
        if (u >= 0 && u < 64 * 128) {
            int nc = u >> 7, k = u & 127;
            W2t[u] = f2bf(W2[k * 64 + nc]);
        }
        return;
    }
    __shared__ int h[512];
    int t = threadIdx.x;
    int e0 = blockIdx.x * PB;
    int cnt = min(PB, E - e0);
    for (int b = t; b < NB; b += 256) h[b] = 0;
    __syncthreads();
    for (int i = t; i < cnt; i += 256)
        atomicAdd(&h[dst[e0 + i] >> BSH], 1);
    __syncthreads();
    for (int b = t; b < NB; b += 256)
        if (h[b]) atomicAdd(&bcnt[b], h[b]);
}

// cursors start at ZERO (part1 adds bbase[b] itself).
__global__ void bscan(const int* __restrict__ bcnt, int* __restrict__ bbase,
                      int* __restrict__ bcur, int NB, int E) {
    __shared__ int s[512];
    int t = threadIdx.x;
    int v = (t < NB) ? bcnt[t] : 0;
    s[t] = v;
    __syncthreads();
    for (int o = 1; o < 512; o <<= 1) {
        int add = (t >= o) ? s[t - o] : 0;
        __syncthreads();
        s[t] += add;
        __syncthreads();
    }
    if (t < NB) { bbase[t] = s[t] - v; bcur[t] = 0; }
    if (t == 0) bbase[NB] = E;
}

// ---------------- MFMA GEMM body (shared by standalone + fused kernels) ---------
// C[n,OUT] = A[n,128] @ W[128,OUT] -> fp8 out. bf16 in, fp32 acc.
// Layouts (m89/m91-verified): A[m=lane&15][k=quad*8+j], B[k=quad*8+j][n=lane&15],
// C/D col=lane&15 row=quad*4+reg.

template <int OUT, bool AFP32>
static __device__ __forceinline__ void gemm_body(
    unsigned short* As, unsigned short* Ws,
    const void* __restrict__ Av, const unsigned short* __restrict__ Wt,
    uchar* __restrict__ C, int n, int row0, int t) {
    constexpr int AP = 72;    // A chunk pitch (64+8)
    constexpr int WP = 136;   // W pitch (128+8)
    constexpr int NT = OUT / 16;

    for (int i = t; i < OUT * 16; i += 256) {
        int rr = i >> 4, sq = i & 15;
        *(uint4*)&Ws[rr * WP + sq * 8] = *(const uint4*)(Wt + rr * 128 + sq * 8);
    }

    const int w = t >> 6, l = t & 63;
    const int q = l >> 4, r16 = l & 15;
    const int mbase = w * 32;

    f32x4 acc0[NT], acc1[NT];
    for (int i = 0; i < NT; i++) {
        acc0[i] = (f32x4){0.f, 0.f, 0.f, 0.f};
        acc1[i] = (f32x4){0.f, 0.f, 0.f, 0.f};
    }

    for (int half = 0; half < 2; half++) {
        if (half) __syncthreads();
        if (AFP32) {
            const float* A = (const float*)Av;
            for (int i = t; i < 128 * 16; i += 256) {
                int rr = i >> 4, fq = i & 15;
                float4 v = make_float4(0.f, 0.f, 0.f, 0.f);
                if (row0 + rr < n)
                    v = *(const float4*)(A + (size_t)(row0 + rr) * 128 + half * 64 + fq * 4);
                unsigned short* p = &As[rr * AP + fq * 4];
                p[0] = f2bf(v.x); p[1] = f2bf(v.y); p[2] = f2bf(v.z); p[3] = f2bf(v.w);
            }
        } else {
            const unsigned short* A = (const unsigned short*)Av;
            for (int i = t; i < 128 * 8; i += 256) {
                int rr = i >> 3, sq = i & 7;
                uint4 v = make_uint4(0, 0, 0, 0);
                if (row0 + rr < n)
                    v = *(const uint4*)(A + (size_t)(row0 + rr) * 128 + half * 64 + sq * 8);
                *(uint4*)&As[rr * AP + sq * 8] = v;
            }
        }
        __syncthreads();

#pragma unroll
        for (int kc = 0; kc < 2; kc++) {
            int ko = kc * 32 + q * 8;
            int kow = half * 64 + ko;
            bf16x8 a0 = *(const bf16x8*)&As[(mbase + r16) * AP + ko];
            bf16x8 a1 = *(const bf16x8*)&As[(mbase + 16 + r16) * AP + ko];
#pragma unroll
            for (int nt = 0; nt < NT; nt++) {
                bf16x8 b = *(const bf16x8*)&Ws[(nt * 16 + r16) * WP + kow];
                acc0[nt] = __builtin_amdgcn_mfma_f32_16x16x32_bf16(a0, b, acc0[nt], 0, 0, 0);
                acc1[nt] = __builtin_amdgcn_mfma_f32_16x16x32_bf16(a1, b, acc1[nt], 0, 0, 0);
            }
        }
    }

#pragma unroll
    for (int nt = 0; nt < NT; nt++) {
#pragma unroll
        for (int p = 0; p < 4; p++) {
            int rr = row0 + mbase + q * 4 + p;
            if (rr < n) C[(size_t)rr * OUT + nt * 16 + r16] = f2fp8(acc0[nt][p]);
            if (rr + 16 < n) C[(size_t)(rr + 16) * OUT + nt * 16 + r16] = f2fp8(acc1[nt][p]);
        }
    }
}

// Fused: blocks < gP run part1 (LDS-cached partition); the rest run GEMM1.
// part1 and GEMM1 are data-independent; co-residency overlaps part1's
// latency-bound phase with GEMM1's compute. LDS union: max(36.9, 53.2) KB.
__global__ __launch_bounds__(256) void part1_gemm1(
    const int* __restrict__ src, const int* __restrict__ dst,
    const int* __restrict__ bbase, int* __restrict__ bcur,
    int2* __restrict__ pairBuf, int E, int NB, int gP,
    const float* __restrict__ x, const unsigned short* __restrict__ W1t,
    uchar* __restrict__ H1, int n) {
    __shared__ __align__(16) char smem[53248];
    int t = threadIdx.x;

    if ((int)blockIdx.x >= gP) {
        unsigned short* As = (unsigned short*)smem;            // 18432 B
        unsigned short* Ws = (unsigned short*)(smem + 18432);  // 34816 B
        gemm_body<128, true>(As, Ws, x, W1t, H1, n, ((int)blockIdx.x - gP) * 128, t);
        return;
    }

    int2* pairs = (int2*)smem;                      // 32768 B
    int*  hist  = (int*)(smem + 32768);             // 2048 B
    int*  base  = (int*)(smem + 32768 + 2048);      // 2048 B
    int e0 = blockIdx.x * PB;
    int cnt = min(PB, E - e0);
    for (int b = t; b < NB; b += 256) hist[b] = 0;
    __syncthreads();
    for (int i = t; i < cnt; i += 256) {
        int s = src[e0 + i], d = dst[e0 + i];
        pairs[i] = make_int2(s, d);
        atomicAdd(&hist[d >> BSH], 1);
    }
    __syncthreads();
    for (int b = t; b < NB; b += 256) {
        int h = hist[b];
        int gb = (h > 0) ? atomicAdd(&bcur[b], h) : 0;
        base[b] = bbase[b] + gb;
        hist[b] = 0;
    }
    __syncthreads();
    for (int i = t; i < cnt; i += 256) {
        int2 p = pairs[i];
        int b = p.y >> BSH;
        int q = base[b] + atomicAdd(&hist[b], 1);
        pairBuf[q] = p;
    }
}

__global__ __launch_bounds__(256) void bucket_build(
    const int2* __restrict__ pairBuf, const int* __restrict__ bbase,
    int* __restrict__ rowptr, int* __restrict__ deg, float* __restrict__ dinv,
    int* __restrict__ csr, int N) {
    __shared__ int cnt[256];
    __shared__ int loc[256];
    int b = blockIdx.x, t = threadIdx.x;
    int start = bbase[b], end = bbase[b + 1];
    cnt[t] = 0;
    __syncthreads();
    for (int i = start + t; i < end; i += 256)
        atomicAdd(&cnt[pairBuf[i].y & 255], 1);
    __syncthreads();
    int v = cnt[t];
    loc[t] = v;
    __syncthreads();
    for (int o = 1; o < 256; o <<= 1) {
        int add = (t >= o) ? loc[t - o] : 0;
        __syncthreads();
        loc[t] += add;
        __syncthreads();
    }
    int excl = loc[t] - v;
    int node = (b << BSH) + t;
    if (node < N) {
        rowptr[node] = start + excl;
        deg[node] = v;
        dinv[node] = rsqrtf((float)(v + 2));   // +2 self-loops
    }
    __syncthreads();
    cnt[t] = excl;                              // reuse as cursor
    __syncthreads();
    for (int i = start + t; i < end; i += 256) {
        int2 p = pairBuf[i];
        int q = start + atomicAdd(&cnt[p.y & 255], 1);
        csr[q] = p.x;
    }
}

// Standalone GEMM (layer 2).
template <int OUT, bool AFP32>
__global__ __launch_bounds__(256) void gemm_mfma(
    const void* __restrict__ Av, const unsigned short* __restrict__ Wt,
    uchar* __restrict__ C, int n) {
    __shared__ unsigned short As[128 * 72];
    __shared__ unsigned short Ws[OUT * 136];
    gemm_body<OUT, AFP32>(As, Ws, Av, Wt, C, n, blockIdx.x * 128, threadIdx.x);
}

// ---------------- Aggregation: QUARTER-WAVE per node, packed f32 FMA ------------
// 16 lanes own one node; wave streams 4 nodes. Accumulators are f32x2 so
// acc += w2*d selects v_pk_fma_f32 (2 FMAs/instr). cvt_pk_f32_fp8 feeds pairs.

// agg1: 128 ch, lane covers 8 ch (uint2 = 8 fp8). out = bf16.
__global__ __launch_bounds__(256) void agg_relu_128(
    const uchar* __restrict__ H, const int* __restrict__ csr,
    const int* __restrict__ rowptr, const int* __restrict__ deg,
    const float* __restrict__ dinv, const float* __restrict__ bias,
    unsigned short* __restrict__ out, int n) {
    int v = blockIdx.x * 16 + (threadIdx.x >> 4);
    int hl = threadIdx.x & 15;
    int gsel = threadIdx.x & 48;
    bool valid = v < n;
    int vc = valid ? v : 0;
    int base = rowptr[vc];
    int cnt = valid ? deg[vc] : 0;

    f32x2 acc[4][4];
#pragma unroll
    for (int i = 0; i < 4; i++)
#pragma unroll
        for (int p = 0; p < 4; p++) acc[i][p] = (f32x2){0.f, 0.f};

    for (int j0 = 0; j0 < cnt; j0 += 16) {
        int nj = min(16, cnt - j0);
        int ul = 0; float wl = 0.f;
        if (hl < nj) { ul = csr[base + j0 + hl]; wl = dinv[ul]; }
        int j = 0;
        for (; j + 4 <= nj; j += 4) {
            int s0 = j | gsel, s1 = (j + 1) | gsel, s2 = (j + 2) | gsel, s3 = (j + 3) | gsel;
            int u0 = __shfl(ul, s0), u1 = __shfl(ul, s1);
            int u2 = __shfl(ul, s2), u3 = __shfl(ul, s3);
            float w0 = __shfl(wl, s0), w1 = __shfl(wl, s1);
            float w2 = __shfl(wl, s2), w3 = __shfl(wl, s3);
            uint2 h0 = *(const uint2*)(H + (size_t)u0 * 128 + hl * 8);
            uint2 h1 = *(const uint2*)(H + (size_t)u1 * 128 + hl * 8);
            uint2 h2 = *(const uint2*)(H + (size_t)u2 * 128 + hl * 8);
            uint2 h3 = *(const uint2*)(H + (size_t)u3 * 128 + hl * 8);
            f32x2 wv;
            wv = (f32x2){w0, w0};
            acc[0][0] += wv * __builtin_amdgcn_cvt_pk_f32_fp8(h0.x, false);
            acc[0][1] += wv * __builtin_amdgcn_cvt_pk_f32_fp8(h0.x, true);
            acc[0][2] += wv * __builtin_amdgcn_cvt_pk_f32_fp8(h0.y, false);
            acc[0][3] += wv * __builtin_amdgcn_cvt_pk_f32_fp8(h0.y, true);
            wv = (f32x2){w1, w1};
            acc[1][0] += wv * __builtin_amdgcn_cvt_pk_f32_fp8(h1.x, false);
            acc[1][1] += wv * __builtin_amdgcn_cvt_pk_f32_fp8(h1.x, true);
            acc[1][2] += wv * __builtin_amdgcn_cvt_pk_f32_fp8(h1.y, false);
            acc[1][3] += wv * __builtin_amdgcn_cvt_pk_f32_fp8(h1.y, true);
            wv = (f32x2){w2, w2};
            acc[2][0] += wv * __builtin_amdgcn_cvt_pk_f32_fp8(h2.x, false);
            acc[2][1] += wv * __builtin_amdgcn_cvt_pk_f32_fp8(h2.x, true);
            acc[2][2] += wv * __builtin_amdgcn_cvt_pk_f32_fp8(h2.y, false);
            acc[2][3] += wv * __builtin_amdgcn_cvt_pk_f32_fp8(h2.y, true);
            wv = (f32x2){w3, w3};
            acc[3][0] += wv * __builtin_amdgcn_cvt_pk_f32_fp8(h3.x, false);
            acc[3][1] += wv * __builtin_amdgcn_cvt_pk_f32_fp8(h3.x, true);
            acc[3][2] += wv * __builtin_amdgcn_cvt_pk_f32_fp8(h3.y, false);
            acc[3][3] += wv * __builtin_amdgcn_cvt_pk_f32_fp8(h3.y, true);
        }
        for (; j < nj; j++) {
            int s = j | gsel;
            int u = __shfl(ul, s);
            float wf = __shfl(wl, s);
            uint2 h = *(const uint2*)(H + (size_t)u * 128 + hl * 8);
            f32x2 wv = (f32x2){wf, wf};
            acc[0][0] += wv * __builtin_amdgcn_cvt_pk_f32_fp8(h.x, false);
            acc[0][1] += wv * __builtin_amdgcn_cvt_pk_f32_fp8(h.x, true);
            acc[0][2] += wv * __builtin_amdgcn_cvt_pk_f32_fp8(h.y, false);
            acc[0][3] += wv * __builtin_amdgcn_cvt_pk_f32_fp8(h.y, true);
        }
    }
    if (valid) {
        f32x2 a0 = (acc[0][0] + acc[1][0]) + (acc[2][0] + acc[3][0]);
        f32x2 a1 = (acc[0][1] + acc[1][1]) + (acc[2][1] + acc[3][1]);
        f32x2 a2 = (acc[0][2] + acc[1][2]) + (acc[2][2] + acc[3][2]);
        f32x2 a3 = (acc[0][3] + acc[1][3]) + (acc[2][3] + acc[3][3]);
        float dv = dinv[vc];
        float sl = 2.f * dv * dv;
        uint2 hv = *(const uint2*)(H + (size_t)vc * 128 + hl * 8);
        f32x2 s0 = __builtin_amdgcn_cvt_pk_f32_fp8(hv.x, false);
        f32x2 s1 = __builtin_amdgcn_cvt_pk_f32_fp8(hv.x, true);
        f32x2 s2 = __builtin_amdgcn_cvt_pk_f32_fp8(hv.y, false);
        f32x2 s3 = __builtin_amdgcn_cvt_pk_f32_fp8(hv.y, true);
        const float4* bp = (const float4*)(bias + hl * 8);
        float4 b0 = bp[0], b1 = bp[1];
        float o0 = fmaxf(dv * a0[0] + sl * s0[0] + b0.x, 0.f);
        float o1 = fmaxf(dv * a0[1] + sl * s0[1] + b0.y, 0.f);
        float o2 = fmaxf(dv * a1[0] + sl * s1[0] + b0.z, 0.f);
        float o3 = fmaxf(dv * a1[1] + sl * s1[1] + b0.w, 0.f);
        float o4 = fmaxf(dv * a2[0] + sl * s2[0] + b1.x, 0.f);
        float o5 = fmaxf(dv * a2[1] + sl * s2[1] + b1.y, 0.f);
        float o6 = fmaxf(dv * a3[0] + sl * s3[0] + b1.z, 0.f);
        float o7 = fmaxf(dv * a3[1] + sl * s3[1] + b1.w, 0.f);
        uint4 pk;
        pk.x = (uint32)f2bf(o0) | ((uint32)f2bf(o1) << 16);
        pk.y = (uint32)f2bf(o2) | ((uint32)f2bf(o3) << 16);
        pk.z = (uint32)f2bf(o4) | ((uint32)f2bf(o5) << 16);
        pk.w = (uint32)f2bf(o6) | ((uint32)f2bf(o7) << 16);
        *(uint4*)(out + (size_t)vc * 128 + hl * 8) = pk;
    }
}

// agg2: 64 ch, lane covers 4 ch (uint = 4 fp8). log_softmax within group of 16.
__global__ __launch_bounds__(256) void agg_lsm_64(
    const uchar* __restrict__ H, const int* __restrict__ csr,
    const int* __restrict__ rowptr, const int* __restrict__ deg,
    const float* __restrict__ dinv, const float* __restrict__ bias,
    float* __restrict__ out, int n) {
    int v = blockIdx.x * 16 + (threadIdx.x >> 4);
    int hl = threadIdx.x & 15;
    int gsel = threadIdx.x & 48;
    bool valid = v < n;
    int vc = valid ? v : 0;
    int base = rowptr[vc];
    int cnt = valid ? deg[vc] : 0;

    f32x2 acc[4][2];
#pragma unroll
    for (int i = 0; i < 4; i++) {
        acc[i][0] = (f32x2){0.f, 0.f};
        acc[i][1] = (f32x2){0.f, 0.f};
    }

    for (int j0 = 0; j0 < cnt; j0 += 16) {
        int nj = min(16, cnt - j0);
        int ul = 0; float wl = 0.f;
        if (hl < nj) { ul = csr[base + j0 + hl]; wl = dinv[ul]; }
        int j = 0;
        for (; j + 4 <= nj; j += 4) {
            int s0 = j | gsel, s1 = (j + 1) | gsel, s2 = (j + 2) | gsel, s3 = (j + 3) | gsel;
            int u0 = __shfl(ul, s0), u1 = __shfl(ul, s1);
            int u2 = __shfl(ul, s2), u3 = __shfl(ul, s3);
            float w0 = __shfl(wl, s0), w1 = __shfl(wl, s1);
            float w2 = __shfl(wl, s2), w3 = __shfl(wl, s3);
            uint32 h0 = *(const uint32*)(H + (size_t)u0 * 64 + hl * 4);
            uint32 h1 = *(const uint32*)(H + (size_t)u1 * 64 + hl * 4);
            uint32 h2 = *(const uint32*)(H + (size_t)u2 * 64 + hl * 4);
            uint32 h3 = *(const uint32*)(H + (size_t)u3 * 64 + hl * 4);
            f32x2 wv;
            wv = (f32x2){w0, w0};
            acc[0][0] += wv * __builtin_amdgcn_cvt_pk_f32_fp8(h0, false);
            acc[0][1] += wv * __builtin_amdgcn_cvt_pk_f32_fp8(h0, true);
            wv = (f32x2){w1, w1};
            acc[1][0] += wv * __builtin_amdgcn_cvt_pk_f32_fp8(h1, false);
            acc[1][1] += wv * __builtin_amdgcn_cvt_pk_f32_fp8(h1, true);
            wv = (f32x2){w2, w2};
            acc[2][0] += wv * __builtin_amdgcn_cvt_pk_f32_fp8(h2, false);
            acc[2][1] += wv * __builtin_amdgcn_cvt_pk_f32_fp8(h2, true);
            wv = (f32x2){w3, w3};
            acc[3][0] += wv * __builtin_amdgcn_cvt_pk_f32_fp8(h3, false);
            acc[3][1] += wv * __builtin_amdgcn_cvt_pk_f32_fp8(h3, true);
        }
        for (; j < nj; j++) {
            int s = j | gsel;
            int u = __shfl(ul, s);
            float wf = __shfl(wl, s);
            uint32 h = *(const uint32*)(H + (size_t)u * 64 + hl * 4);
            f32x2 wv = (f32x2){wf, wf};
            acc[0][0] += wv * __builtin_amdgcn_cvt_pk_f32_fp8(h, false);
            acc[0][1] += wv * __builtin_amdgcn_cvt_pk_f32_fp8(h, true);
        }
    }
    f32x2 aL = (acc[0][0] + acc[1][0]) + (acc[2][0] + acc[3][0]);
    f32x2 aH = (acc[0][1] + acc[1][1]) + (acc[2][1] + acc[3][1]);
    float dv = dinv[vc];
    uint32 hv = *(const uint32*)(H + (size_t)vc * 64 + hl * 4);
    f32x2 dl = __builtin_amdgcn_cvt_pk_f32_fp8(hv, false);
    f32x2 dh = __builtin_amdgcn_cvt_pk_f32_fp8(hv, true);
    float4 bb = ((const float4*)bias)[hl];
    float sl = 2.f * dv * dv;
    float v0 = dv * aL[0] + sl * dl[0] + bb.x;
    float v1 = dv * aL[1] + sl * dl[1] + bb.y;
    float v2 = dv * aH[0] + sl * dh[0] + bb.z;
    float v3 = dv * aH[1] + sl * dh[1] + bb.w;
    float m = fmaxf(fmaxf(v0, v1), fmaxf(v2, v3));
    for (int o = 8; o > 0; o >>= 1) m = fmaxf(m, __shfl_xor(m, o));
    float e = (__expf(v0 - m) + __expf(v1 - m)) + (__expf(v2 - m) + __expf(v3 - m));
    for (int o = 8; o > 0; o >>= 1) e += __shfl_xor(e, o);
    float ls = m + __logf(e);
    if (valid)
        *(float4*)(out + (size_t)vc * 64 + hl * 4) =
            make_float4(v0 - ls, v1 - ls, v2 - ls, v3 - ls);
}

// ---------------- launch ----------------

extern "C" void kernel_launch(void* const* d_in, const int* in_sizes, int n_in,
                              void* d_out, int out_size, void* d_ws, size_t ws_size,
                              hipStream_t stream) {
    const float* x  = (const float*)d_in[0];
    const int*   ei = (const int*)d_in[1];
    const float* W1 = (const float*)d_in[2];
    const float* b1 = (const float*)d_in[3];
    const float* W2 = (const float*)d_in[4];
    const float* b2 = (const float*)d_in[5];
    float* out = (float*)d_out;

    const int N = in_sizes[0] / IN_CH;  // 100000
    const int E = in_sizes[1] / 2;      // 1600000
    const int* src = ei;
    const int* dst = ei + E;
    const int NB = (N + 255) >> BSH;    // 391 buckets

    char* w = (char*)d_ws;
    size_t off = 0;
    auto alloc = [&](size_t bytes) -> char* {
        char* p = w + off;
        off = (off + bytes + 255) & ~(size_t)255;
        return p;
    };
    int*   deg    = (int*)alloc((size_t)N * 4);
    int*   rowptr = (int*)alloc((size_t)N * 4);
    int*   bcnt   = (int*)alloc(512 * 4);
    int*   bbase  = (int*)alloc(513 * 4);
    int*   bcur   = (int*)alloc(512 * 4);
    float* dinv   = (float*)alloc((size_t)N * 4);
    int*   csr    = (int*)alloc((size_t)E * 4);
    unsigned short* W1t = (unsigned short*)alloc(128 * 128 * 2);
    unsigned short* W2t = (unsigned short*)alloc(64 * 128 * 2);
    uchar* H1  = (uchar*)alloc((size_t)N * HID_CH);          // fp8, 12.8 MB
    unsigned short* A1b = (unsigned short*)alloc((size_t)N * HID_CH * 2);  // bf16
    uchar* H2  = H1;                     // fp8; H1 dead after agg1
    int2*  pairBuf = (int2*)A1b;         // A1b not written until agg1 (after bucket_build)

    hipMemsetAsync(bcnt, 0, 512 * 4, stream);

    int gP = (E + PB - 1) / PB;         // 391 partition blocks
    int gG1 = (N + 127) / 128;          // 782 GEMM1 blocks

    bhist_wtrans<<<gP + 96, 256, 0, stream>>>(dst, bcnt, E, NB, gP, W1, W2, W1t, W2t);
    bscan<<<1, 512, 0, stream>>>(bcnt, bbase, bcur, NB, E);
    part1_gemm1<<<gP + gG1, 256, 0, stream>>>(src, dst, bbase, bcur, pairBuf, E, NB, gP,
                                              x, W1t, H1, N);
    bucket_build<<<NB, 256, 0, stream>>>(pairBuf, bbase, rowptr, deg, dinv, csr, N);

    agg_relu_128<<<(N + 15) / 16, 256, 0, stream>>>(H1, csr, rowptr, deg, dinv, b1, A1b, N);
    gemm_mfma<64, false><<<(N + 127) / 128, 256, 0, stream>>>(A1b, W2t, H2, N);
    agg_lsm_64<<<(N + 15) / 16, 256, 0, stream>>>(H2, csr, rowptr, deg, dinv, b2, out, N);
}